// Round 7
// baseline (324.612 us; speedup 1.0000x reference)
//
#include <hip/hip_runtime.h>
#include <cstddef>
#include <cmath>

#define NB  4096
#define TT  200
#define DD  64
#define NH1 80
#define NH2 40

typedef _Float16 half8 __attribute__((ext_vector_type(8)));
typedef float    f32x4 __attribute__((ext_vector_type(4)));

// ---- workspace layout (bytes) ----
// wQh [4096][80] f32 : q@(W1a+W1c) + b1
// wF1 : layer-1 B fragments, lane-major: [(n*4+s)*64 + lane] -> half8  (20480 B)
// wF2 : layer-2 B fragments, lane-major: [(n*3+s)*64 + lane] -> half8  (9216 B)
static const size_t OFF_QH = 0;
static const size_t OFF_F1 = (size_t)NB * NH1 * 4;
static const size_t OFF_F2 = OFF_F1 + (size_t)5 * 4 * 64 * 8 * 2;

__global__ void prep_weights(const float* __restrict__ W1, const float* __restrict__ W2,
                             _Float16* __restrict__ wF1, _Float16* __restrict__ wF2)
{
    const int tid = blockIdx.x * blockDim.x + threadIdx.x;
    const int stride = blockDim.x * gridDim.x;
    // layer-1 fragments: value = B[kk][h], h = n*16+(l&15), kk = s*32+(l>>4)*8+j
    for (int i = tid; i < 5 * 4 * 64 * 8; i += stride) {
        const int j = i & 7, l = (i >> 3) & 63, s = (i >> 9) & 3, n = i >> 11;
        const int h  = n * 16 + (l & 15);
        const int kk = s * 32 + (l >> 4) * 8 + j;
        const float w = (kk < 64) ? (W1[(64 + kk) * NH1 + h] - W1[(128 + kk) * NH1 + h])
                                  :  W1[(128 + kk) * NH1 + h];
        wF1[i] = (_Float16)w;
    }
    // layer-2 fragments: value = W2[kk][n2], n2 = n*16+(l&15), kk = s*32+(l>>4)*8+j
    for (int i = tid; i < 3 * 3 * 64 * 8; i += stride) {
        const int j = i & 7, l = (i >> 3) & 63;
        const int s = (i >> 9) % 3, n = i / 1536;
        const int kk = s * 32 + (l >> 4) * 8 + j;
        const int n2 = n * 16 + (l & 15);
        const float w = (kk < NH1 && n2 < NH2) ? W2[kk * NH2 + n2] : 0.f;
        wF2[i] = (_Float16)w;
    }
}

__global__ void prep_qh(const float* __restrict__ q, const float* __restrict__ W1,
                        const float* __restrict__ b1, float* __restrict__ wQh)
{
    const int idx = blockIdx.x * blockDim.x + threadIdx.x;
    if (idx >= NB * NH1) return;
    const int b = idx / NH1;
    const int h = idx - b * NH1;
    const float* qb = q + (size_t)b * DD;
    float acc = b1[h];
#pragma unroll 8
    for (int d = 0; d < DD; ++d)
        acc += qb[d] * (W1[d * NH1 + h] + W1[(128 + d) * NH1 + h]);
    wQh[idx] = acc;
}

// one wave per b; group-split online softmax; k register double-buffer;
// both weight layers staged in LDS to fit the (256,3) register budget
__global__ __launch_bounds__(256, 3)
void attn_main(const float* __restrict__ q, const float* __restrict__ k,
               const float* __restrict__ v, const int* __restrict__ mask,
               const float* __restrict__ Wf, const float* __restrict__ b2g,
               const float* __restrict__ bf,
               const float* __restrict__ wQh, const _Float16* __restrict__ wF1,
               const _Float16* __restrict__ wF2, float* __restrict__ out)
{
    __shared__ __align__(16) _Float16 sWF1[5 * 4 * 64 * 8];   // 20480 B
    __shared__ __align__(16) _Float16 sWF2[3 * 3 * 64 * 8];   //  9216 B
    __shared__ __align__(16) char sH1[4 * 3072];              // per-wave h1, swizzled
    __shared__ __align__(16) float sBias[4][208];             // per-wave mask bias

    const int tid  = threadIdx.x;
    const int wid  = tid >> 6;
    const int lane = tid & 63;
    const int lr   = lane & 15;
    const int lg   = lane >> 4;
    const int b    = blockIdx.x * 4 + wid;      // each wave owns one batch row
    const int d0   = lr * 4;                    // this lane's v/out column slice
    const float bfv = bf[0];

    // stage layer-1 + layer-2 weight fragments into LDS (block-shared)
    {
        f32x4* dst1 = (f32x4*)sWF1;
        const f32x4* src1 = (const f32x4*)wF1;
        for (int i = tid; i < 1280; i += 256) dst1[i] = src1[i];
        f32x4* dst2 = (f32x4*)sWF2;
        const f32x4* src2 = (const f32x4*)wF2;
        for (int i = tid; i < 576; i += 256) dst2[i] = src2[i];
    }

    // per-wave mask bias: +big = keep, CONST_MIN = masked, -inf = pad rows (t>=200)
    for (int i = lane; i < 208; i += 64) {
        float bv;
        if (i < TT) bv = mask[(size_t)b * TT + i] ? 3.0e38f : -4294967295.0f;
        else        bv = -INFINITY;
        sBias[wid][i] = bv;
    }

    // per-lane slices of qh / Wf / b2
    float qhr[5];
#pragma unroll
    for (int n = 0; n < 5; ++n) qhr[n] = wQh[(size_t)b * NH1 + n * 16 + lr];
    float wfr[3], bbr[3];
#pragma unroll
    for (int n = 0; n < 3; ++n) {
        const int hc = n * 16 + lr;
        wfr[n] = (hc < NH2) ? Wf[hc]  : 0.f;
        bbr[n] = (hc < NH2) ? b2g[hc] : 0.f;
    }

    // q in packed fp16
    half8 qh0, qh1;
    {
        const float* qb = q + (size_t)b * DD;
#pragma unroll
        for (int j = 0; j < 8; ++j) qh0[j] = (_Float16)qb[lg * 8 + j];
#pragma unroll
        for (int j = 0; j < 8; ++j) qh1[j] = (_Float16)qb[32 + lg * 8 + j];
    }

    // zero-pad my wave's h1 cols 80..95 (slots 10,11), swizzled
    char* myH1 = sH1 + wid * 3072;
    if (lane < 32) {
        const int row = lane >> 1;
        const int slotL = 10 + (lane & 1);
        const f32x4 z4 = {};
        *(f32x4*)(myH1 + row * 192 + ((slotL ^ (row & 3)) << 4)) = z4;
    }

    __syncthreads();   // sWF1 / sWF2 ready

    const half8* sF1v = (const half8*)sWF1;
    const half8* sF2v = (const half8*)sWF2;
    const float* vb   = v + (size_t)b * (TT * DD);

    // per-GROUP online softmax state (rows mt*16+lg*4+{0..3}; d-cols d0..d0+3)
    float m = -INFINITY, s = 0.f;
    f32x4 acc = {};

    // prologue: k tile 0 into registers
    f32x4 kc0, kc1, kc2, kc3;
    {
        const float* krow = k + ((size_t)b * TT + lr) * DD;
        kc0 = *(const f32x4*)(krow + lg * 8);
        kc1 = *(const f32x4*)(krow + lg * 8 + 4);
        kc2 = *(const f32x4*)(krow + 32 + lg * 8);
        kc3 = *(const f32x4*)(krow + 32 + lg * 8 + 4);
    }

    for (int mt = 0; mt < 13; ++mt) {
        // ---- v loads for this tile (issued early; consumed at bottom) ----
        const int tr = mt * 16 + lg * 4;
        const f32x4 vA = *(const f32x4*)(vb + (size_t)min(tr + 0, TT - 1) * DD + d0);
        const f32x4 vB = *(const f32x4*)(vb + (size_t)min(tr + 1, TT - 1) * DD + d0);
        const f32x4 vC = *(const f32x4*)(vb + (size_t)min(tr + 2, TT - 1) * DD + d0);
        const f32x4 vD = *(const f32x4*)(vb + (size_t)min(tr + 3, TT - 1) * DD + d0);

        // ---- convert current k to fp16 A-fragments ----
        half8 af0, af1;
#pragma unroll
        for (int j = 0; j < 4; ++j) {
            af0[j] = (_Float16)kc0[j];  af0[j + 4] = (_Float16)kc1[j];
            af1[j] = (_Float16)kc2[j];  af1[j + 4] = (_Float16)kc3[j];
        }
        const half8 af2 = qh0 * af0;
        const half8 af3 = qh1 * af1;

        // ---- prefetch next k tile (register double-buffer) ----
        if (mt < 12) {
            const int t = min((mt + 1) * 16 + lr, TT - 1);
            const float* krow = k + ((size_t)b * TT + t) * DD;
            kc0 = *(const f32x4*)(krow + lg * 8);
            kc1 = *(const f32x4*)(krow + lg * 8 + 4);
            kc2 = *(const f32x4*)(krow + 32 + lg * 8);
            kc3 = *(const f32x4*)(krow + 32 + lg * 8 + 4);
        }

        // ---- layer 1 MFMA, qh folded into C-init, relu -> per-wave LDS ----
#pragma unroll
        for (int n = 0; n < 5; ++n) {
            f32x4 a = { qhr[n], qhr[n], qhr[n], qhr[n] };
            a = __builtin_amdgcn_mfma_f32_16x16x32_f16(af0, sF1v[(n * 4 + 0) * 64 + lane], a, 0, 0, 0);
            a = __builtin_amdgcn_mfma_f32_16x16x32_f16(af1, sF1v[(n * 4 + 1) * 64 + lane], a, 0, 0, 0);
            a = __builtin_amdgcn_mfma_f32_16x16x32_f16(af2, sF1v[(n * 4 + 2) * 64 + lane], a, 0, 0, 0);
            a = __builtin_amdgcn_mfma_f32_16x16x32_f16(af3, sF1v[(n * 4 + 3) * 64 + lane], a, 0, 0, 0);
            const int slot   = (n * 16 + lr) >> 3;
            const int within = ((n * 16 + lr) & 7) * 2;
#pragma unroll
            for (int j = 0; j < 4; ++j) {
                const int r = lg * 4 + j;
                const float hv = fmaxf(a[j], 0.f);
                *(_Float16*)(myH1 + r * 192 + ((slot ^ (r & 3)) << 4) + within) = (_Float16)hv;
            }
        }

        // ---- layer 2 (wave-private rows), b2 folded into C-init ----
        half8 a2_0 = *(const half8*)(myH1 + lr * 192 + (((0 * 4 + lg) ^ (lr & 3)) << 4));
        half8 a2_1 = *(const half8*)(myH1 + lr * 192 + (((1 * 4 + lg) ^ (lr & 3)) << 4));
        half8 a2_2 = *(const half8*)(myH1 + lr * 192 + (((2 * 4 + lg) ^ (lr & 3)) << 4));

        float p0 = 0.f, p1 = 0.f, p2 = 0.f, p3 = 0.f;
#pragma unroll
        for (int n = 0; n < 3; ++n) {
            f32x4 c2 = { bbr[n], bbr[n], bbr[n], bbr[n] };
            c2 = __builtin_amdgcn_mfma_f32_16x16x32_f16(a2_0, sF2v[(n * 3 + 0) * 64 + lane], c2, 0, 0, 0);
            c2 = __builtin_amdgcn_mfma_f32_16x16x32_f16(a2_1, sF2v[(n * 3 + 1) * 64 + lane], c2, 0, 0, 0);
            c2 = __builtin_amdgcn_mfma_f32_16x16x32_f16(a2_2, sF2v[(n * 3 + 2) * 64 + lane], c2, 0, 0, 0);
            p0 = fmaf(fmaxf(c2[0], 0.f), wfr[n], p0);
            p1 = fmaf(fmaxf(c2[1], 0.f), wfr[n], p1);
            p2 = fmaf(fmaxf(c2[2], 0.f), wfr[n], p2);
            p3 = fmaf(fmaxf(c2[3], 0.f), wfr[n], p3);
        }
        // butterfly over the 16-lane column group: rows lg*4+{0..3} summed
#pragma unroll
        for (int off = 1; off < 16; off <<= 1) {
            p0 += __shfl_xor(p0, off);
            p1 += __shfl_xor(p1, off);
            p2 += __shfl_xor(p2, off);
            p3 += __shfl_xor(p3, off);
        }

        // ---- group-private online masked softmax + v accumulation ----
        const f32x4 bias4 = *(const f32x4*)&sBias[wid][mt * 16 + lg * 4];
        const float l0 = fminf(p0, bias4[0]) + bfv;
        const float l1 = fminf(p1, bias4[1]) + bfv;
        const float l2 = fminf(p2, bias4[2]) + bfv;
        const float l3 = fminf(p3, bias4[3]) + bfv;
        const float lmax = fmaxf(fmaxf(l0, l1), fmaxf(l2, l3));
        const float mnew = fmaxf(m, lmax);
        const float sc = __expf(m - mnew);
        const float w0 = __expf(l0 - mnew);
        const float w1 = __expf(l1 - mnew);
        const float w2 = __expf(l2 - mnew);
        const float w3 = __expf(l3 - mnew);
        s = s * sc + (w0 + w1 + w2 + w3);
        acc *= sc;
        acc += vA * w0;
        acc += vB * w1;
        acc += vC * w2;
        acc += vD * w3;
        m = mnew;
    }

    // ---- merge the 4 group states (lanes differ in bits 4,5) ----
    float mo = fmaxf(m, __shfl_xor(m, 16));
    mo = fmaxf(mo, __shfl_xor(mo, 32));
    const float f = __expf(m - mo);
    s *= f;
    acc *= f;
    s += __shfl_xor(s, 16);
    s += __shfl_xor(s, 32);
#pragma unroll
    for (int e = 0; e < 4; ++e) {
        float t = acc[e];
        t += __shfl_xor(t, 16);
        t += __shfl_xor(t, 32);
        acc[e] = t;
    }
    if (lg == 0) {
        const f32x4 res = acc / s;
        *(f32x4*)(out + (size_t)b * DD + d0) = res;
    }
}

extern "C" void kernel_launch(void* const* d_in, const int* in_sizes, int n_in,
                              void* d_out, int out_size, void* d_ws, size_t ws_size,
                              hipStream_t stream)
{
    const float* q   = (const float*)d_in[0];
    const float* k   = (const float*)d_in[1];
    const float* v   = (const float*)d_in[2];
    const int*  mask = (const int*)  d_in[3];
    const float* W1  = (const float*)d_in[4];
    const float* b1  = (const float*)d_in[5];
    const float* W2  = (const float*)d_in[6];
    const float* b2  = (const float*)d_in[7];
    const float* Wf  = (const float*)d_in[8];
    const float* bf  = (const float*)d_in[9];
    float* out = (float*)d_out;

    char* ws = (char*)d_ws;
    float*    wQh = (float*)   (ws + OFF_QH);
    _Float16* wF1 = (_Float16*)(ws + OFF_F1);
    _Float16* wF2 = (_Float16*)(ws + OFF_F2);

    prep_weights<<<16, 256, 0, stream>>>(W1, W2, wF1, wF2);
    prep_qh<<<(NB * NH1 + 255) / 256, 256, 0, stream>>>(q, W1, b1, wQh);
    attn_main<<<NB / 4, 256, 0, stream>>>(q, k, v, mask, Wf, b2, bf, wQh, wF1, wF2, out);
}

// Round 8
// 100.715 us; speedup vs baseline: 3.2231x; 3.2231x over previous
//
#include <hip/hip_runtime.h>
#include <cstddef>
#include <cmath>

#define NB  4096
#define TT  200
#define DD  64
#define NH1 80
#define NH2 40

typedef _Float16 half8 __attribute__((ext_vector_type(8)));
typedef float    f32x4 __attribute__((ext_vector_type(4)));

// ---- workspace layout (bytes) ----
// wQh [4096][80] f32 : q@(W1a+W1c) + b1
// wF1 : layer-1 B fragments, lane-major: [(n*4+s)*64 + lane] -> half8  (20480 B)
// wF2 : layer-2 B fragments, lane-major: [(n*3+s)*64 + lane] -> half8  (9216 B)
static const size_t OFF_QH = 0;
static const size_t OFF_F1 = (size_t)NB * NH1 * 4;
static const size_t OFF_F2 = OFF_F1 + (size_t)5 * 4 * 64 * 8 * 2;

__global__ void prep_weights(const float* __restrict__ W1, const float* __restrict__ W2,
                             _Float16* __restrict__ wF1, _Float16* __restrict__ wF2)
{
    const int tid = blockIdx.x * blockDim.x + threadIdx.x;
    const int stride = blockDim.x * gridDim.x;
    // layer-1 fragments: value = B[kk][h], h = n*16+(l&15), kk = s*32+(l>>4)*8+j
    for (int i = tid; i < 5 * 4 * 64 * 8; i += stride) {
        const int j = i & 7, l = (i >> 3) & 63, s = (i >> 9) & 3, n = i >> 11;
        const int h  = n * 16 + (l & 15);
        const int kk = s * 32 + (l >> 4) * 8 + j;
        const float w = (kk < 64) ? (W1[(64 + kk) * NH1 + h] - W1[(128 + kk) * NH1 + h])
                                  :  W1[(128 + kk) * NH1 + h];
        wF1[i] = (_Float16)w;
    }
    // layer-2 fragments: value = W2[kk][n2], n2 = n*16+(l&15), kk = s*32+(l>>4)*8+j
    for (int i = tid; i < 3 * 3 * 64 * 8; i += stride) {
        const int j = i & 7, l = (i >> 3) & 63;
        const int s = (i >> 9) % 3, n = i / 1536;
        const int kk = s * 32 + (l >> 4) * 8 + j;
        const int n2 = n * 16 + (l & 15);
        const float w = (kk < NH1 && n2 < NH2) ? W2[kk * NH2 + n2] : 0.f;
        wF2[i] = (_Float16)w;
    }
}

__global__ void prep_qh(const float* __restrict__ q, const float* __restrict__ W1,
                        const float* __restrict__ b1, float* __restrict__ wQh)
{
    const int idx = blockIdx.x * blockDim.x + threadIdx.x;
    if (idx >= NB * NH1) return;
    const int b = idx / NH1;
    const int h = idx - b * NH1;
    const float* qb = q + (size_t)b * DD;
    float acc = b1[h];
#pragma unroll 8
    for (int d = 0; d < DD; ++d)
        acc += qb[d] * (W1[d * NH1 + h] + W1[(128 + d) * NH1 + h]);
    wQh[idx] = acc;
}

// one wave per b; group-split online softmax; k register double-buffer;
// ALL weight fragments register-resident (loop-invariant) -> LDS pipe freed
__global__ __launch_bounds__(256, 2)
void attn_main(const float* __restrict__ q, const float* __restrict__ k,
               const float* __restrict__ v, const int* __restrict__ mask,
               const float* __restrict__ Wf, const float* __restrict__ b2g,
               const float* __restrict__ bf,
               const float* __restrict__ wQh, const _Float16* __restrict__ wF1,
               const _Float16* __restrict__ wF2, float* __restrict__ out)
{
    __shared__ __align__(16) char sH1[4 * 3072];              // per-wave h1, swizzled
    __shared__ __align__(16) float sBias[4][208];             // per-wave mask bias

    const int tid  = threadIdx.x;
    const int wid  = tid >> 6;
    const int lane = tid & 63;
    const int lr   = lane & 15;
    const int lg   = lane >> 4;
    const int b    = blockIdx.x * 4 + wid;      // each wave owns one batch row
    const int d0   = lr * 4;                    // this lane's v/out column slice
    const float bfv = bf[0];

    // weight fragments -> registers (loop-invariant; L2-resident images)
    half8 w1f[20];
#pragma unroll
    for (int i = 0; i < 20; ++i) w1f[i] = ((const half8*)wF1)[i * 64 + lane];
    half8 w2f[9];
#pragma unroll
    for (int i = 0; i < 9; ++i) w2f[i] = ((const half8*)wF2)[i * 64 + lane];

    // per-wave mask bias: +big = keep, CONST_MIN = masked, -inf = pad rows (t>=200)
    for (int i = lane; i < 208; i += 64) {
        float bv;
        if (i < TT) bv = mask[(size_t)b * TT + i] ? 3.0e38f : -4294967295.0f;
        else        bv = -INFINITY;
        sBias[wid][i] = bv;
    }

    // per-lane slices of qh / Wf / b2
    float qhr[5];
#pragma unroll
    for (int n = 0; n < 5; ++n) qhr[n] = wQh[(size_t)b * NH1 + n * 16 + lr];
    float wfr[3], bbr[3];
#pragma unroll
    for (int n = 0; n < 3; ++n) {
        const int hc = n * 16 + lr;
        wfr[n] = (hc < NH2) ? Wf[hc]  : 0.f;
        bbr[n] = (hc < NH2) ? b2g[hc] : 0.f;
    }

    // q in packed fp16
    half8 qh0, qh1;
    {
        const float* qb = q + (size_t)b * DD;
#pragma unroll
        for (int j = 0; j < 8; ++j) qh0[j] = (_Float16)qb[lg * 8 + j];
#pragma unroll
        for (int j = 0; j < 8; ++j) qh1[j] = (_Float16)qb[32 + lg * 8 + j];
    }

    // zero-pad my wave's h1 cols 80..95 (slots 10,11), swizzled
    char* myH1 = sH1 + wid * 3072;
    if (lane < 32) {
        const int row = lane >> 1;
        const int slotL = 10 + (lane & 1);
        const f32x4 z4 = {};
        *(f32x4*)(myH1 + row * 192 + ((slotL ^ (row & 3)) << 4)) = z4;
    }

    __syncthreads();   // cheap; orders the wave-private LDS init conservatively

    const float* vb = v + (size_t)b * (TT * DD);

    // per-GROUP online softmax state (rows mt*16+lg*4+{0..3}; d-cols d0..d0+3)
    float m = -INFINITY, s = 0.f;
    f32x4 acc = {};

    // prologue: k tile 0 into registers
    f32x4 kc0, kc1, kc2, kc3;
    {
        const float* krow = k + ((size_t)b * TT + lr) * DD;
        kc0 = *(const f32x4*)(krow + lg * 8);
        kc1 = *(const f32x4*)(krow + lg * 8 + 4);
        kc2 = *(const f32x4*)(krow + 32 + lg * 8);
        kc3 = *(const f32x4*)(krow + 32 + lg * 8 + 4);
    }

    for (int mt = 0; mt < 13; ++mt) {
        // ---- v loads for this tile (issued early; consumed at bottom) ----
        const int tr = mt * 16 + lg * 4;
        const f32x4 vA = *(const f32x4*)(vb + (size_t)min(tr + 0, TT - 1) * DD + d0);
        const f32x4 vB = *(const f32x4*)(vb + (size_t)min(tr + 1, TT - 1) * DD + d0);
        const f32x4 vC = *(const f32x4*)(vb + (size_t)min(tr + 2, TT - 1) * DD + d0);
        const f32x4 vD = *(const f32x4*)(vb + (size_t)min(tr + 3, TT - 1) * DD + d0);

        // ---- convert current k to fp16 A-fragments ----
        half8 af0, af1;
#pragma unroll
        for (int j = 0; j < 4; ++j) {
            af0[j] = (_Float16)kc0[j];  af0[j + 4] = (_Float16)kc1[j];
            af1[j] = (_Float16)kc2[j];  af1[j + 4] = (_Float16)kc3[j];
        }
        const half8 af2 = qh0 * af0;
        const half8 af3 = qh1 * af1;

        // ---- prefetch next k tile (register double-buffer) ----
        if (mt < 12) {
            const int t = min((mt + 1) * 16 + lr, TT - 1);
            const float* krow = k + ((size_t)b * TT + t) * DD;
            kc0 = *(const f32x4*)(krow + lg * 8);
            kc1 = *(const f32x4*)(krow + lg * 8 + 4);
            kc2 = *(const f32x4*)(krow + 32 + lg * 8);
            kc3 = *(const f32x4*)(krow + 32 + lg * 8 + 4);
        }

        // ---- layer 1 MFMA (register B-fragments), qh in C-init, relu -> LDS ----
#pragma unroll
        for (int n = 0; n < 5; ++n) {
            f32x4 a = { qhr[n], qhr[n], qhr[n], qhr[n] };
            a = __builtin_amdgcn_mfma_f32_16x16x32_f16(af0, w1f[n * 4 + 0], a, 0, 0, 0);
            a = __builtin_amdgcn_mfma_f32_16x16x32_f16(af1, w1f[n * 4 + 1], a, 0, 0, 0);
            a = __builtin_amdgcn_mfma_f32_16x16x32_f16(af2, w1f[n * 4 + 2], a, 0, 0, 0);
            a = __builtin_amdgcn_mfma_f32_16x16x32_f16(af3, w1f[n * 4 + 3], a, 0, 0, 0);
            const int slot   = (n * 16 + lr) >> 3;
            const int within = ((n * 16 + lr) & 7) * 2;
#pragma unroll
            for (int j = 0; j < 4; ++j) {
                const int r = lg * 4 + j;
                const float hv = fmaxf(a[j], 0.f);
                *(_Float16*)(myH1 + r * 192 + ((slot ^ (r & 3)) << 4) + within) = (_Float16)hv;
            }
        }

        // ---- layer 2 (wave-private rows), b2 folded into C-init ----
        half8 a2_0 = *(const half8*)(myH1 + lr * 192 + (((0 * 4 + lg) ^ (lr & 3)) << 4));
        half8 a2_1 = *(const half8*)(myH1 + lr * 192 + (((1 * 4 + lg) ^ (lr & 3)) << 4));
        half8 a2_2 = *(const half8*)(myH1 + lr * 192 + (((2 * 4 + lg) ^ (lr & 3)) << 4));

        float p0 = 0.f, p1 = 0.f, p2 = 0.f, p3 = 0.f;
#pragma unroll
        for (int n = 0; n < 3; ++n) {
            f32x4 c2 = { bbr[n], bbr[n], bbr[n], bbr[n] };
            c2 = __builtin_amdgcn_mfma_f32_16x16x32_f16(a2_0, w2f[n * 3 + 0], c2, 0, 0, 0);
            c2 = __builtin_amdgcn_mfma_f32_16x16x32_f16(a2_1, w2f[n * 3 + 1], c2, 0, 0, 0);
            c2 = __builtin_amdgcn_mfma_f32_16x16x32_f16(a2_2, w2f[n * 3 + 2], c2, 0, 0, 0);
            p0 = fmaf(fmaxf(c2[0], 0.f), wfr[n], p0);
            p1 = fmaf(fmaxf(c2[1], 0.f), wfr[n], p1);
            p2 = fmaf(fmaxf(c2[2], 0.f), wfr[n], p2);
            p3 = fmaf(fmaxf(c2[3], 0.f), wfr[n], p3);
        }
        // butterfly over the 16-lane column group: rows lg*4+{0..3} summed
#pragma unroll
        for (int off = 1; off < 16; off <<= 1) {
            p0 += __shfl_xor(p0, off);
            p1 += __shfl_xor(p1, off);
            p2 += __shfl_xor(p2, off);
            p3 += __shfl_xor(p3, off);
        }

        // ---- group-private online masked softmax + v accumulation ----
        const f32x4 bias4 = *(const f32x4*)&sBias[wid][mt * 16 + lg * 4];
        const float l0 = fminf(p0, bias4[0]) + bfv;
        const float l1 = fminf(p1, bias4[1]) + bfv;
        const float l2 = fminf(p2, bias4[2]) + bfv;
        const float l3 = fminf(p3, bias4[3]) + bfv;
        const float lmax = fmaxf(fmaxf(l0, l1), fmaxf(l2, l3));
        const float mnew = fmaxf(m, lmax);
        const float sc = __expf(m - mnew);
        const float w0 = __expf(l0 - mnew);
        const float w1 = __expf(l1 - mnew);
        const float w2 = __expf(l2 - mnew);
        const float w3 = __expf(l3 - mnew);
        s = s * sc + (w0 + w1 + w2 + w3);
        acc *= sc;
        acc += vA * w0;
        acc += vB * w1;
        acc += vC * w2;
        acc += vD * w3;
        m = mnew;
    }

    // ---- merge the 4 group states (lanes differ in bits 4,5) ----
    float mo = fmaxf(m, __shfl_xor(m, 16));
    mo = fmaxf(mo, __shfl_xor(mo, 32));
    const float f = __expf(m - mo);
    s *= f;
    acc *= f;
    s += __shfl_xor(s, 16);
    s += __shfl_xor(s, 32);
#pragma unroll
    for (int e = 0; e < 4; ++e) {
        float t = acc[e];
        t += __shfl_xor(t, 16);
        t += __shfl_xor(t, 32);
        acc[e] = t;
    }
    if (lg == 0) {
        const f32x4 res = acc / s;
        *(f32x4*)(out + (size_t)b * DD + d0) = res;
    }
}

extern "C" void kernel_launch(void* const* d_in, const int* in_sizes, int n_in,
                              void* d_out, int out_size, void* d_ws, size_t ws_size,
                              hipStream_t stream)
{
    const float* q   = (const float*)d_in[0];
    const float* k   = (const float*)d_in[1];
    const float* v   = (const float*)d_in[2];
    const int*  mask = (const int*)  d_in[3];
    const float* W1  = (const float*)d_in[4];
    const float* b1  = (const float*)d_in[5];
    const float* W2  = (const float*)d_in[6];
    const float* b2  = (const float*)d_in[7];
    const float* Wf  = (const float*)d_in[8];
    const float* bf  = (const float*)d_in[9];
    float* out = (float*)d_out;

    char* ws = (char*)d_ws;
    float*    wQh = (float*)   (ws + OFF_QH);
    _Float16* wF1 = (_Float16*)(ws + OFF_F1);
    _Float16* wF2 = (_Float16*)(ws + OFF_F2);

    prep_weights<<<16, 256, 0, stream>>>(W1, W2, wF1, wF2);
    prep_qh<<<(NB * NH1 + 255) / 256, 256, 0, stream>>>(q, W1, b1, wQh);
    attn_main<<<NB / 4, 256, 0, stream>>>(q, k, v, mask, Wf, b2, bf, wQh, wF1, wF2, out);
}